// Round 13
// baseline (400.467 us; speedup 1.0000x reference)
//
#include <hip/hip_runtime.h>
#include <hip/hip_fp16.h>
#include <math.h>

#define DD 64      // per-head channels
#define HH 8       // heads
#define HD 512     // HH*DD
#define NC 1024    // combined xl|xr row width

typedef __attribute__((ext_vector_type(8))) short bf16x8;
typedef __attribute__((ext_vector_type(4))) float f32x4;
typedef __attribute__((ext_vector_type(8))) unsigned short ushort8;

// ---------------------------------------------------------------------------
// bf16 split helpers (round-to-nearest-even)
// ---------------------------------------------------------------------------
__device__ __forceinline__ ushort bf16_rne(float f) {
    uint u = __float_as_uint(f);
    u += 0x7fffu + ((u >> 16) & 1u);
    return (ushort)(u >> 16);
}
__device__ __forceinline__ float bf16_tof(ushort h) {
    return __uint_as_float(((uint)h) << 16);
}
__device__ __forceinline__ float h2f(ushort u) {
    __half h; *reinterpret_cast<ushort*>(&h) = u; return __half2float(h);
}

// elementwise fp32 -> (hi, lo) bf16 pair
__global__ __launch_bounds__(256) void split_mat(const float* __restrict__ in,
                                                 ushort* __restrict__ hi,
                                                 ushort* __restrict__ lo, int total)
{
    const int i = blockIdx.x * 256 + threadIdx.x;
    if (i >= total) return;
    const float f = in[i];
    const ushort h = bf16_rne(f);
    hi[i] = h;
    lo[i] = bf16_rne(f - bf16_tof(h));
}

// W0,W1: [K][512] fp32 -> Bt: [1024][K] bf16 hi/lo (transposed, concatenated)
__global__ __launch_bounds__(256) void split_wT(const float* __restrict__ W0,
                                                const float* __restrict__ W1,
                                                ushort* __restrict__ hi,
                                                ushort* __restrict__ lo, int kshift)
{
    const int K = 1 << kshift;
    const int i = blockIdx.x * 256 + threadIdx.x;    // i = c*K + k
    if (i >= 1024 * K) return;
    const int c = i >> kshift, k = i & (K - 1);
    const float* W = (c < 512) ? W0 : W1;
    const float f = W[(size_t)k * 512 + (c & 511)];
    const ushort h = bf16_rne(f);
    hi[i] = h;
    lo[i] = bf16_rne(f - bf16_tof(h));
}

// ---------------------------------------------------------------------------
// bf16x3 split-precision MFMA GEMM, NO-LDS variant: MFMA fragments are
// loaded directly from global as 16B/lane vectors (the fragment pattern IS
// a contiguous 16B-per-lane access). No barriers, no vmcnt(0) drain — the
// compiler pipelines loads across K-steps with counted waits. B (2MB) is
// L2-resident across all M-tiles; wave-pairs' duplicate A reads hit L1.
// A-rows clamped branch-free (C-write masks OOB rows).
// ---------------------------------------------------------------------------
template<int K>
__global__ __launch_bounds__(256) void gemm_nolds(
    const ushort* __restrict__ Ah, const ushort* __restrict__ Al,
    const ushort* __restrict__ Bh, const ushort* __restrict__ Bl,
    __half* __restrict__ C, int M)
{
    const int nwg = gridDim.x;                        // 8*MT, divisible by 8
    const int wg  = (blockIdx.x & 7) * (nwg >> 3) + (blockIdx.x >> 3);
    const int ntile = wg & 7, mtile = wg >> 3;
    const int bm = mtile * 128, bn = ntile * 128;

    const int tid  = threadIdx.x;
    const int wid  = tid >> 6;            // 0..3
    const int lane = tid & 63;
    const int wr = wid >> 1, wc = wid & 1;   // 2x2 wave quadrants (64x64)
    const int l15 = lane & 15, g = lane >> 4;

    // fragment base pointers: lane (l15,g) covers k = g*8..g*8+7 of its row
    const ushort* pAh[4]; const ushort* pAl[4];
    const ushort* pBh[4]; const ushort* pBl[4];
    #pragma unroll
    for (int m = 0; m < 4; ++m) {
        const size_t r = (size_t)min(bm + wr * 64 + m * 16 + l15, M - 1) * K + g * 8;
        pAh[m] = Ah + r; pAl[m] = Al + r;
    }
    #pragma unroll
    for (int n = 0; n < 4; ++n) {
        const size_t r = (size_t)(bn + wc * 64 + n * 16 + l15) * K + g * 8;
        pBh[n] = Bh + r; pBl[n] = Bl + r;
    }

    f32x4 acc[4][4] = {};

    for (int k0 = 0; k0 < K; k0 += 32) {     // one 32-K MFMA slice per step
        bf16x8 ah[4], al[4], bh[4], bl[4];
        #pragma unroll
        for (int m = 0; m < 4; ++m) {
            ah[m] = *(const bf16x8*)(pAh[m] + k0);
            al[m] = *(const bf16x8*)(pAl[m] + k0);
        }
        #pragma unroll
        for (int n = 0; n < 4; ++n) {
            bh[n] = *(const bf16x8*)(pBh[n] + k0);
            bl[n] = *(const bf16x8*)(pBl[n] + k0);
        }
        #pragma unroll
        for (int m = 0; m < 4; ++m)
            #pragma unroll
            for (int n = 0; n < 4; ++n) {
                acc[m][n] = __builtin_amdgcn_mfma_f32_16x16x32_bf16(
                                ah[m], bh[n], acc[m][n], 0, 0, 0);
                acc[m][n] = __builtin_amdgcn_mfma_f32_16x16x32_bf16(
                                ah[m], bl[n], acc[m][n], 0, 0, 0);
                acc[m][n] = __builtin_amdgcn_mfma_f32_16x16x32_bf16(
                                al[m], bh[n], acc[m][n], 0, 0, 0);
            }
    }

    // C write: D frag (row=(g*4+i), col=l15) at (wr*64+m*16, wc*64+n*16)
    #pragma unroll
    for (int m = 0; m < 4; ++m) {
        #pragma unroll
        for (int i = 0; i < 4; ++i) {
            const int row = bm + wr * 64 + m * 16 + g * 4 + i;
            if (row >= M) continue;
            __half* cp = C + (size_t)row * NC + bn + wc * 64 + l15;
            #pragma unroll
            for (int n = 0; n < 4; ++n)
                cp[n * 16] = __float2half_rn(acc[m][n][i]);
        }
    }
}

// ---------------------------------------------------------------------------
// CSR build (per launch; edge list identical for both layers).
// ---------------------------------------------------------------------------
__global__ __launch_bounds__(256) void hist_deg(const int* __restrict__ dsts,
                                                int E, int ET, int* __restrict__ deg)
{
    const int w = blockIdx.x * blockDim.x + threadIdx.x;
    if (w >= ET) return;
    const int d = (w < E) ? dsts[w] : (w - E);   // w >= E: virtual self-loop
    atomicAdd(&deg[d], 1);
}

// single-block exclusive scan, 1024-wide (was 256: 4x serial-chunk work)
__global__ __launch_bounds__(1024) void scan_rowptr(const int* __restrict__ deg,
                                                    int* __restrict__ rowptr,
                                                    int* __restrict__ cursor, int n)
{
    __shared__ int sums[1024];
    const int tid   = threadIdx.x;
    const int chunk = (n + 1023) / 1024;
    const int lo = min(tid * chunk, n), hi = min(lo + chunk, n);

    int s = 0;
    for (int i = lo; i < hi; ++i) s += deg[i];
    sums[tid] = s;
    __syncthreads();

    for (int off = 1; off < 1024; off <<= 1) {
        const int t = (tid >= off) ? sums[tid - off] : 0;
        __syncthreads();
        sums[tid] += t;
        __syncthreads();
    }

    int run = sums[tid] - s;   // exclusive prefix of this chunk
    for (int i = lo; i < hi; ++i) {
        rowptr[i] = run;
        cursor[i] = run;
        run += deg[i];
    }
    if (tid == 1023) rowptr[n] = run;   // == ET
}

__global__ __launch_bounds__(256) void scatter_csr(const int* __restrict__ srcs,
                                                   const int* __restrict__ dsts,
                                                   int E, int ET,
                                                   int* __restrict__ cursor,
                                                   int* __restrict__ eidx)
{
    const int w = blockIdx.x * blockDim.x + threadIdx.x;
    if (w >= ET) return;
    int s, d;
    if (w < E) { s = srcs[w]; d = dsts[w]; }
    else       { s = w - E;   d = s; }
    const int pos = atomicAdd(&cursor[d], 1);
    eidx[pos] = s;
}

// ---------------------------------------------------------------------------
// Fused GATv2 edge pipeline + epilogue (unchanged from round 12).
// ONE wave per dst node; lane owns 8 contiguous channels (head = lane>>3).
// ---------------------------------------------------------------------------
__device__ __forceinline__ void edge_step(const ushort8 v,
                                          const float* __restrict__ r,
                                          const float* __restrict__ a,
                                          float* __restrict__ acc, float& den)
{
    float vf[8], s = 0.f;
    #pragma unroll
    for (int j = 0; j < 8; ++j) {
        vf[j] = h2f(v[j]);
        float t = vf[j] + r[j];
        t = t > 0.f ? t : 0.2f * t;          // leaky_relu(0.2)
        s = fmaf(t, a[j], s);
    }
    s += __shfl_xor(s, 1, 64);               // reduce within 8-lane head group
    s += __shfl_xor(s, 2, 64);
    s += __shfl_xor(s, 4, 64);
    const float p = __expf(s);               // logits O(1): no max shift
    den += p;
    #pragma unroll
    for (int j = 0; j < 8; ++j) acc[j] = fmaf(p, vf[j], acc[j]);
}

template<int MODE>
__global__ __launch_bounds__(256) void gat_fused(
    const __half* __restrict__ xlr, const float* __restrict__ att,
    const float* __restrict__ bias, const int* __restrict__ rowptr,
    const int* __restrict__ eidx, int n, float* __restrict__ out,
    ushort* __restrict__ oh, ushort* __restrict__ ol)
{
    const int d    = (blockIdx.x * blockDim.x + threadIdx.x) >> 6;
    const int lane = threadIdx.x & 63;
    if (d >= n) return;

    const int o = lane * 8;                  // channels [o, o+8)

    // xr row (fp16) and att (fp32) -> registers
    float r[8], a[8];
    {
        const ushort8 rv = *(const ushort8*)((const ushort*)xlr + (size_t)d * NC + 512 + o);
        #pragma unroll
        for (int j = 0; j < 8; ++j) r[j] = h2f(rv[j]);
        *(float4*)&a[0] = *(const float4*)(att + o);
        *(float4*)&a[4] = *(const float4*)(att + o + 4);
    }

    float acc[8] = {};
    float den = 0.f;

    const int start = rowptr[d];
    const int end   = rowptr[d + 1];         // deg >= 1 (self-loop)
    const int last  = end - 1;
    const ushort* xb = (const ushort*)xlr;

    ushort8 v0 = *(const ushort8*)(xb + ((size_t)eidx[start] << 10) + o);
    ushort8 v1 = *(const ushort8*)(xb + ((size_t)eidx[min(start + 1, last)] << 10) + o);

    int e = start;
    for (; e + 1 < end; e += 2) {
        const int i2 = min(e + 2, last), i3 = min(e + 3, last);
        const ushort8 n0 = *(const ushort8*)(xb + ((size_t)eidx[i2] << 10) + o);
        const ushort8 n1 = *(const ushort8*)(xb + ((size_t)eidx[i3] << 10) + o);
        edge_step(v0, r, a, acc, den);
        edge_step(v1, r, a, acc, den);
        v0 = n0; v1 = n1;
    }
    if (e < end) edge_step(v0, r, a, acc, den);

    const float inv = 1.f / den;

    if (MODE == 0) {
        // elu(agg + b1), emitted as bf16 hi/lo split for the next GEMM
        float bv[8];
        *(float4*)&bv[0] = *(const float4*)(bias + o);
        *(float4*)&bv[4] = *(const float4*)(bias + o + 4);
        ushort8 hx, lx;
        #pragma unroll
        for (int j = 0; j < 8; ++j) {
            const float u = fmaf(acc[j], inv, bv[j]);
            const float w = u > 0.f ? u : expm1f(u);
            const ushort h = bf16_rne(w);
            hx[j] = h;
            lx[j] = bf16_rne(w - bf16_tof(h));
        }
        *(ushort8*)(oh + (size_t)d * HD + o) = hx;
        *(ushort8*)(ol + (size_t)d * HD + o) = lx;
    } else {
        // mean over 8 heads: reduce across lane bits 3,4,5
        float m[8];
        #pragma unroll
        for (int j = 0; j < 8; ++j) m[j] = acc[j] * inv;
        #pragma unroll
        for (int j = 0; j < 8; ++j) {
            m[j] += __shfl_xor(m[j], 8,  64);
            m[j] += __shfl_xor(m[j], 16, 64);
            m[j] += __shfl_xor(m[j], 32, 64);
        }
        if (lane < 8) {                      // lane covers channels lane*8..+7
            const int c = lane * 8;
            float4 r0, r1;
            r0.x = fmaf(m[0], 0.125f, bias[c + 0]);
            r0.y = fmaf(m[1], 0.125f, bias[c + 1]);
            r0.z = fmaf(m[2], 0.125f, bias[c + 2]);
            r0.w = fmaf(m[3], 0.125f, bias[c + 3]);
            r1.x = fmaf(m[4], 0.125f, bias[c + 4]);
            r1.y = fmaf(m[5], 0.125f, bias[c + 5]);
            r1.z = fmaf(m[6], 0.125f, bias[c + 6]);
            r1.w = fmaf(m[7], 0.125f, bias[c + 7]);
            *(float4*)(out + (size_t)d * DD + c)     = r0;
            *(float4*)(out + (size_t)d * DD + c + 4) = r1;
        }
    }
}

// ---------------------------------------------------------------------------
extern "C" void kernel_launch(void* const* d_in, const int* in_sizes, int n_in,
                              void* d_out, int out_size, void* d_ws, size_t ws_size,
                              hipStream_t stream)
{
    const float* x    = (const float*)d_in[0];
    const int*   ei   = (const int*)  d_in[1];
    const float* Wl1  = (const float*)d_in[2];
    const float* Wr1  = (const float*)d_in[3];
    const float* att1 = (const float*)d_in[4];
    const float* b1   = (const float*)d_in[5];
    const float* Wl2  = (const float*)d_in[6];
    const float* Wr2  = (const float*)d_in[7];
    const float* att2 = (const float*)d_in[8];
    const float* b2   = (const float*)d_in[9];

    const int N  = in_sizes[0] / DD;   // 20000
    const int E  = in_sizes[1] / 2;    // 320000
    const int ET = E + N;              // edges + self-loops

    const int* srcs = ei;
    const int* dsts = ei + E;

    // ---- workspace layout ----
    __half* xlr   = (__half*)d_ws;                      // N*1024 f16 (41 MB)
    ushort* xs_h  = (ushort*)(xlr + (size_t)N * NC);    // N*64
    ushort* xs_l  = xs_h  + (size_t)N * DD;             // N*64
    ushort* h1_h  = xs_l  + (size_t)N * DD;             // N*512
    ushort* h1_l  = h1_h  + (size_t)N * HD;             // N*512
    ushort* bt1_h = h1_l  + (size_t)N * HD;             // 1024*64
    ushort* bt1_l = bt1_h + 1024 * DD;                  // 1024*64
    ushort* bt2_h = bt1_l + 1024 * DD;                  // 1024*512
    ushort* bt2_l = bt2_h + 1024 * HD;                  // 1024*512
    int* rowptr = (int*)(bt2_l + 1024 * HD);            // N+1
    int* deg    = rowptr + (N + 1);                     // N
    int* cursor = deg + N;                              // N
    int* eidx   = cursor + N;                           // ET

    const dim3 gblk(256);
    const int  eblk  = (ET + 255) / 256;
    const int  nblk  = (N + 3) / 4;            // one WAVE per node, 4 nodes/block
    const int  MT    = (N + 127) / 128;        // 157
    const int  gemm_grid = 8 * MT;             // 1256, divisible by 8

    // ---- CSR build (shared by both layers) ----
    hipMemsetAsync(deg, 0, (size_t)N * sizeof(int), stream);
    hist_deg   <<<eblk, gblk, 0, stream>>>(dsts, E, ET, deg);
    scan_rowptr<<<1, 1024, 0, stream>>>(deg, rowptr, cursor, N);
    scatter_csr<<<eblk, gblk, 0, stream>>>(srcs, dsts, E, ET, cursor, eidx);

    // ---- split inputs / weights to bf16 hi/lo ----
    split_mat<<<(N * DD + 255) / 256, gblk, 0, stream>>>(x, xs_h, xs_l, N * DD);
    split_wT <<<(1024 * DD + 255) / 256, gblk, 0, stream>>>(Wl1, Wr1, bt1_h, bt1_l, 6);
    split_wT <<<(1024 * HD + 255) / 256, gblk, 0, stream>>>(Wl2, Wr2, bt2_h, bt2_l, 9);

    // ---- layer 1: GATv2Conv(64 -> 64, heads=8, concat) + ELU ----
    gemm_nolds<64><<<gemm_grid, gblk, 0, stream>>>(xs_h, xs_l, bt1_h, bt1_l, xlr, N);
    gat_fused<0><<<nblk, gblk, 0, stream>>>(xlr, att1, b1, rowptr, eidx, N,
                                            nullptr, h1_h, h1_l);

    // ---- layer 2: GATv2Conv(512 -> 64, heads=8, mean) ----
    gemm_nolds<512><<<gemm_grid, gblk, 0, stream>>>(h1_h, h1_l, bt2_h, bt2_l, xlr, N);
    gat_fused<1><<<nblk, gblk, 0, stream>>>(xlr, att2, b2, rowptr, eidx, N,
                                            (float*)d_out, nullptr, nullptr);
}

// Round 14
// 287.777 us; speedup vs baseline: 1.3916x; 1.3916x over previous
//
#include <hip/hip_runtime.h>
#include <hip/hip_fp16.h>
#include <math.h>

#define DD 64      // per-head channels
#define HH 8       // heads
#define HD 512     // HH*DD
#define NC 1024    // combined xl|xr row width

typedef __attribute__((ext_vector_type(8))) short bf16x8;
typedef __attribute__((ext_vector_type(4))) float f32x4;
typedef __attribute__((ext_vector_type(8))) unsigned short ushort8;

// ---------------------------------------------------------------------------
// bf16 split helpers (round-to-nearest-even)
// ---------------------------------------------------------------------------
__device__ __forceinline__ ushort bf16_rne(float f) {
    uint u = __float_as_uint(f);
    u += 0x7fffu + ((u >> 16) & 1u);
    return (ushort)(u >> 16);
}
__device__ __forceinline__ float bf16_tof(ushort h) {
    return __uint_as_float(((uint)h) << 16);
}
__device__ __forceinline__ float h2f(ushort u) {
    __half h; *reinterpret_cast<ushort*>(&h) = u; return __half2float(h);
}

// elementwise fp32 -> (hi, lo) bf16 pair
__global__ __launch_bounds__(256) void split_mat(const float* __restrict__ in,
                                                 ushort* __restrict__ hi,
                                                 ushort* __restrict__ lo, int total)
{
    const int i = blockIdx.x * 256 + threadIdx.x;
    if (i >= total) return;
    const float f = in[i];
    const ushort h = bf16_rne(f);
    hi[i] = h;
    lo[i] = bf16_rne(f - bf16_tof(h));
}

// W0,W1: [K][512] fp32 -> Bt: [1024][K] bf16 hi/lo (transposed, concatenated)
__global__ __launch_bounds__(256) void split_wT(const float* __restrict__ W0,
                                                const float* __restrict__ W1,
                                                ushort* __restrict__ hi,
                                                ushort* __restrict__ lo, int kshift)
{
    const int K = 1 << kshift;
    const int i = blockIdx.x * 256 + threadIdx.x;    // i = c*K + k
    if (i >= 1024 * K) return;
    const int c = i >> kshift, k = i & (K - 1);
    const float* W = (c < 512) ? W0 : W1;
    const float f = W[(size_t)k * 512 + (c & 511)];
    const ushort h = bf16_rne(f);
    hi[i] = h;
    lo[i] = bf16_rne(f - bf16_tof(h));
}

// ---------------------------------------------------------------------------
// bf16x3 split-precision MFMA GEMM, 2-PHASE double-buffered pipeline.
// BK=32; LDS row = [hi chunk0..3 | lo chunk0..3] (128B), XOR-swizzled
// (stored chunk = logical ^ (row&7)) -> conflict-free ds_read_b128.
// Double buffer = 2 x (A 16KB + B 16KB) = 64 KB (2 blocks/CU).
// Per K-step: issue next tile's 8 global_load_lds, s_waitcnt vmcnt(8)
// (current tile's loads done, next tile's stay IN FLIGHT across the
// barrier), raw s_barrier, ds_read + 48 MFMA, raw s_barrier. No vmcnt(0)
// drain in the steady-state loop (T3 counted-vmcnt recipe).
// ---------------------------------------------------------------------------
template<int K>
__global__ __launch_bounds__(256) void gemm_2ph(
    const ushort* __restrict__ Ah, const ushort* __restrict__ Al,
    const ushort* __restrict__ Bh, const ushort* __restrict__ Bl,
    __half* __restrict__ C, int M)
{
    constexpr int NT = K / 32;                     // K-steps
    __shared__ __align__(16) ushort lds[2][2][128 * 64]; // [dbuf][A,B][128r x 128B]

    const int nwg = gridDim.x;                     // 8*MT, divisible by 8
    const int wg  = (blockIdx.x & 7) * (nwg >> 3) + (blockIdx.x >> 3);
    const int ntile = wg & 7, mtile = wg >> 3;
    const int bm = mtile * 128, bn = ntile * 128;

    const int tid  = threadIdx.x;
    const int wid  = tid >> 6;            // 0..3
    const int lane = tid & 63;
    const int wr = wid >> 1, wc = wid & 1;   // 2x2 wave quadrants (64x64)
    const int l15 = lane & 15, g = lane >> 4;

    // staging geometry: one gload_lds fills 8 rows x 128B linearly.
    // lane l writes stored chunk (l&7) of row (l>>3); logical chunk
    // lc = (l&7) ^ ((l>>3)&7); lc<4 -> hi source, lc>=4 -> lo source.
    const int r8   = lane >> 3;                    // 0..7
    const int lc   = (lane & 7) ^ r8;              // logical chunk
    const int ksub = (lc & 3) * 8;                 // k offset in 32-slice
    const ushort* baseA = (lc < 4) ? Ah : Al;
    const ushort* baseB = (lc < 4) ? Bh : Bl;
    const ushort* pA[4]; const ushort* pB[4];
    #pragma unroll
    for (int q = 0; q < 4; ++q) {
        const int rowb = wid * 32 + q * 8;
        pA[q] = baseA + (size_t)min(bm + rowb + r8, M - 1) * K + ksub;
        pB[q] = baseB + (size_t)(bn + rowb + r8) * K + ksub;
    }

    f32x4 acc[4][4] = {};

    // prologue: stage tile 0 into buf 0 (8 loads)
    #pragma unroll
    for (int q = 0; q < 4; ++q) {
        const int rowb = wid * 32 + q * 8;
        __builtin_amdgcn_global_load_lds(
            (const __attribute__((address_space(1))) void*)pA[q],
            (__attribute__((address_space(3))) void*)&lds[0][0][rowb * 64], 16, 0, 0);
        __builtin_amdgcn_global_load_lds(
            (const __attribute__((address_space(1))) void*)pB[q],
            (__attribute__((address_space(3))) void*)&lds[0][1][rowb * 64], 16, 0, 0);
    }

    for (int t = 0; t < NT; ++t) {
        const int cur = t & 1;
        if (t + 1 < NT) {
            // issue next tile into the other buffer (safe: end-of-iter
            // barrier of t-1 guaranteed all reads of that buffer done)
            #pragma unroll
            for (int q = 0; q < 4; ++q) {
                const int rowb = wid * 32 + q * 8;
                __builtin_amdgcn_global_load_lds(
                    (const __attribute__((address_space(1))) void*)(pA[q] + (t + 1) * 32),
                    (__attribute__((address_space(3))) void*)&lds[cur ^ 1][0][rowb * 64], 16, 0, 0);
                __builtin_amdgcn_global_load_lds(
                    (const __attribute__((address_space(1))) void*)(pB[q] + (t + 1) * 32),
                    (__attribute__((address_space(3))) void*)&lds[cur ^ 1][1][rowb * 64], 16, 0, 0);
            }
            asm volatile("s_waitcnt vmcnt(8)" ::: "memory");  // cur's 8 done
        } else {
            asm volatile("s_waitcnt vmcnt(0)" ::: "memory");  // drain last
        }
        __builtin_amdgcn_s_barrier();          // publish buf[cur]

        const ushort* bufA = lds[cur][0];
        const ushort* bufB = lds[cur][1];
        bf16x8 ah[4], al[4], bh[4], bl[4];
        #pragma unroll
        for (int m = 0; m < 4; ++m) {
            const int row = wr * 64 + m * 16 + l15;
            const int sh  = (g ^ (row & 7)) << 3;
            ah[m] = *(const bf16x8*)(bufA + row * 64 + sh);
            al[m] = *(const bf16x8*)(bufA + row * 64 + (sh ^ 32));  // (g|4) chunk
        }
        #pragma unroll
        for (int n = 0; n < 4; ++n) {
            const int row = wc * 64 + n * 16 + l15;
            const int sh  = (g ^ (row & 7)) << 3;
            bh[n] = *(const bf16x8*)(bufB + row * 64 + sh);
            bl[n] = *(const bf16x8*)(bufB + row * 64 + (sh ^ 32));
        }
        #pragma unroll
        for (int m = 0; m < 4; ++m)
            #pragma unroll
            for (int n = 0; n < 4; ++n) {
                acc[m][n] = __builtin_amdgcn_mfma_f32_16x16x32_bf16(
                                ah[m], bh[n], acc[m][n], 0, 0, 0);
                acc[m][n] = __builtin_amdgcn_mfma_f32_16x16x32_bf16(
                                ah[m], bl[n], acc[m][n], 0, 0, 0);
                acc[m][n] = __builtin_amdgcn_mfma_f32_16x16x32_bf16(
                                al[m], bh[n], acc[m][n], 0, 0, 0);
            }
        __builtin_amdgcn_s_barrier();          // all reads of buf[cur] done
    }

    // C write: D frag (row=(g*4+i), col=l15) at (wr*64+m*16, wc*64+n*16)
    #pragma unroll
    for (int m = 0; m < 4; ++m) {
        #pragma unroll
        for (int i = 0; i < 4; ++i) {
            const int row = bm + wr * 64 + m * 16 + g * 4 + i;
            if (row >= M) continue;
            __half* cp = C + (size_t)row * NC + bn + wc * 64 + l15;
            #pragma unroll
            for (int n = 0; n < 4; ++n)
                cp[n * 16] = __float2half_rn(acc[m][n][i]);
        }
    }
}

// ---------------------------------------------------------------------------
// CSR build (per launch; edge list identical for both layers).
// ---------------------------------------------------------------------------
__global__ __launch_bounds__(256) void hist_deg(const int* __restrict__ dsts,
                                                int E, int ET, int* __restrict__ deg)
{
    const int w = blockIdx.x * blockDim.x + threadIdx.x;
    if (w >= ET) return;
    const int d = (w < E) ? dsts[w] : (w - E);   // w >= E: virtual self-loop
    atomicAdd(&deg[d], 1);
}

// single-block exclusive scan, 1024-wide
__global__ __launch_bounds__(1024) void scan_rowptr(const int* __restrict__ deg,
                                                    int* __restrict__ rowptr,
                                                    int* __restrict__ cursor, int n)
{
    __shared__ int sums[1024];
    const int tid   = threadIdx.x;
    const int chunk = (n + 1023) / 1024;
    const int lo = min(tid * chunk, n), hi = min(lo + chunk, n);

    int s = 0;
    for (int i = lo; i < hi; ++i) s += deg[i];
    sums[tid] = s;
    __syncthreads();

    for (int off = 1; off < 1024; off <<= 1) {
        const int t = (tid >= off) ? sums[tid - off] : 0;
        __syncthreads();
        sums[tid] += t;
        __syncthreads();
    }

    int run = sums[tid] - s;   // exclusive prefix of this chunk
    for (int i = lo; i < hi; ++i) {
        rowptr[i] = run;
        cursor[i] = run;
        run += deg[i];
    }
    if (tid == 1023) rowptr[n] = run;   // == ET
}

__global__ __launch_bounds__(256) void scatter_csr(const int* __restrict__ srcs,
                                                   const int* __restrict__ dsts,
                                                   int E, int ET,
                                                   int* __restrict__ cursor,
                                                   int* __restrict__ eidx)
{
    const int w = blockIdx.x * blockDim.x + threadIdx.x;
    if (w >= ET) return;
    int s, d;
    if (w < E) { s = srcs[w]; d = dsts[w]; }
    else       { s = w - E;   d = s; }
    const int pos = atomicAdd(&cursor[d], 1);
    eidx[pos] = s;
}

// ---------------------------------------------------------------------------
// Fused GATv2 edge pipeline + epilogue (unchanged from round 12).
// ONE wave per dst node; lane owns 8 contiguous channels (head = lane>>3).
// ---------------------------------------------------------------------------
__device__ __forceinline__ void edge_step(const ushort8 v,
                                          const float* __restrict__ r,
                                          const float* __restrict__ a,
                                          float* __restrict__ acc, float& den)
{
    float vf[8], s = 0.f;
    #pragma unroll
    for (int j = 0; j < 8; ++j) {
        vf[j] = h2f(v[j]);
        float t = vf[j] + r[j];
        t = t > 0.f ? t : 0.2f * t;          // leaky_relu(0.2)
        s = fmaf(t, a[j], s);
    }
    s += __shfl_xor(s, 1, 64);               // reduce within 8-lane head group
    s += __shfl_xor(s, 2, 64);
    s += __shfl_xor(s, 4, 64);
    const float p = __expf(s);               // logits O(1): no max shift
    den += p;
    #pragma unroll
    for (int j = 0; j < 8; ++j) acc[j] = fmaf(p, vf[j], acc[j]);
}

template<int MODE>
__global__ __launch_bounds__(256) void gat_fused(
    const __half* __restrict__ xlr, const float* __restrict__ att,
    const float* __restrict__ bias, const int* __restrict__ rowptr,
    const int* __restrict__ eidx, int n, float* __restrict__ out,
    ushort* __restrict__ oh, ushort* __restrict__ ol)
{
    const int d    = (blockIdx.x * blockDim.x + threadIdx.x) >> 6;
    const int lane = threadIdx.x & 63;
    if (d >= n) return;

    const int o = lane * 8;                  // channels [o, o+8)

    // xr row (fp16) and att (fp32) -> registers
    float r[8], a[8];
    {
        const ushort8 rv = *(const ushort8*)((const ushort*)xlr + (size_t)d * NC + 512 + o);
        #pragma unroll
        for (int j = 0; j < 8; ++j) r[j] = h2f(rv[j]);
        *(float4*)&a[0] = *(const float4*)(att + o);
        *(float4*)&a[4] = *(const float4*)(att + o + 4);
    }

    float acc[8] = {};
    float den = 0.f;

    const int start = rowptr[d];
    const int end   = rowptr[d + 1];         // deg >= 1 (self-loop)
    const int last  = end - 1;
    const ushort* xb = (const ushort*)xlr;

    ushort8 v0 = *(const ushort8*)(xb + ((size_t)eidx[start] << 10) + o);
    ushort8 v1 = *(const ushort8*)(xb + ((size_t)eidx[min(start + 1, last)] << 10) + o);

    int e = start;
    for (; e + 1 < end; e += 2) {
        const int i2 = min(e + 2, last), i3 = min(e + 3, last);
        const ushort8 n0 = *(const ushort8*)(xb + ((size_t)eidx[i2] << 10) + o);
        const ushort8 n1 = *(const ushort8*)(xb + ((size_t)eidx[i3] << 10) + o);
        edge_step(v0, r, a, acc, den);
        edge_step(v1, r, a, acc, den);
        v0 = n0; v1 = n1;
    }
    if (e < end) edge_step(v0, r, a, acc, den);

    const float inv = 1.f / den;

    if (MODE == 0) {
        // elu(agg + b1), emitted as bf16 hi/lo split for the next GEMM
        float bv[8];
        *(float4*)&bv[0] = *(const float4*)(bias + o);
        *(float4*)&bv[4] = *(const float4*)(bias + o + 4);
        ushort8 hx, lx;
        #pragma unroll
        for (int j = 0; j < 8; ++j) {
            const float u = fmaf(acc[j], inv, bv[j]);
            const float w = u > 0.f ? u : expm1f(u);
            const ushort h = bf16_rne(w);
            hx[j] = h;
            lx[j] = bf16_rne(w - bf16_tof(h));
        }
        *(ushort8*)(oh + (size_t)d * HD + o) = hx;
        *(ushort8*)(ol + (size_t)d * HD + o) = lx;
    } else {
        // mean over 8 heads: reduce across lane bits 3,4,5
        float m[8];
        #pragma unroll
        for (int j = 0; j < 8; ++j) m[j] = acc[j] * inv;
        #pragma unroll
        for (int j = 0; j < 8; ++j) {
            m[j] += __shfl_xor(m[j], 8,  64);
            m[j] += __shfl_xor(m[j], 16, 64);
            m[j] += __shfl_xor(m[j], 32, 64);
        }
        if (lane < 8) {                      // lane covers channels lane*8..+7
            const int c = lane * 8;
            float4 r0, r1;
            r0.x = fmaf(m[0], 0.125f, bias[c + 0]);
            r0.y = fmaf(m[1], 0.125f, bias[c + 1]);
            r0.z = fmaf(m[2], 0.125f, bias[c + 2]);
            r0.w = fmaf(m[3], 0.125f, bias[c + 3]);
            r1.x = fmaf(m[4], 0.125f, bias[c + 4]);
            r1.y = fmaf(m[5], 0.125f, bias[c + 5]);
            r1.z = fmaf(m[6], 0.125f, bias[c + 6]);
            r1.w = fmaf(m[7], 0.125f, bias[c + 7]);
            *(float4*)(out + (size_t)d * DD + c)     = r0;
            *(float4*)(out + (size_t)d * DD + c + 4) = r1;
        }
    }
}

// ---------------------------------------------------------------------------
extern "C" void kernel_launch(void* const* d_in, const int* in_sizes, int n_in,
                              void* d_out, int out_size, void* d_ws, size_t ws_size,
                              hipStream_t stream)
{
    const float* x    = (const float*)d_in[0];
    const int*   ei   = (const int*)  d_in[1];
    const float* Wl1  = (const float*)d_in[2];
    const float* Wr1  = (const float*)d_in[3];
    const float* att1 = (const float*)d_in[4];
    const float* b1   = (const float*)d_in[5];
    const float* Wl2  = (const float*)d_in[6];
    const float* Wr2  = (const float*)d_in[7];
    const float* att2 = (const float*)d_in[8];
    const float* b2   = (const float*)d_in[9];

    const int N  = in_sizes[0] / DD;   // 20000
    const int E  = in_sizes[1] / 2;    // 320000
    const int ET = E + N;              // edges + self-loops

    const int* srcs = ei;
    const int* dsts = ei + E;

    // ---- workspace layout ----
    __half* xlr   = (__half*)d_ws;                      // N*1024 f16 (41 MB)
    ushort* xs_h  = (ushort*)(xlr + (size_t)N * NC);    // N*64
    ushort* xs_l  = xs_h  + (size_t)N * DD;             // N*64
    ushort* h1_h  = xs_l  + (size_t)N * DD;             // N*512
    ushort* h1_l  = h1_h  + (size_t)N * HD;             // N*512
    ushort* bt1_h = h1_l  + (size_t)N * HD;             // 1024*64
    ushort* bt1_l = bt1_h + 1024 * DD;                  // 1024*64
    ushort* bt2_h = bt1_l + 1024 * DD;                  // 1024*512
    ushort* bt2_l = bt2_h + 1024 * HD;                  // 1024*512
    int* rowptr = (int*)(bt2_l + 1024 * HD);            // N+1
    int* deg    = rowptr + (N + 1);                     // N
    int* cursor = deg + N;                              // N
    int* eidx   = cursor + N;                           // ET

    const dim3 gblk(256);
    const int  eblk  = (ET + 255) / 256;
    const int  nblk  = (N + 3) / 4;            // one WAVE per node, 4 nodes/block
    const int  MT    = (N + 127) / 128;        // 157
    const int  gemm_grid = 8 * MT;             // 1256, divisible by 8

    // ---- CSR build (shared by both layers) ----
    hipMemsetAsync(deg, 0, (size_t)N * sizeof(int), stream);
    hist_deg   <<<eblk, gblk, 0, stream>>>(dsts, E, ET, deg);
    scan_rowptr<<<1, 1024, 0, stream>>>(deg, rowptr, cursor, N);
    scatter_csr<<<eblk, gblk, 0, stream>>>(srcs, dsts, E, ET, cursor, eidx);

    // ---- split inputs / weights to bf16 hi/lo ----
    split_mat<<<(N * DD + 255) / 256, gblk, 0, stream>>>(x, xs_h, xs_l, N * DD);
    split_wT <<<(1024 * DD + 255) / 256, gblk, 0, stream>>>(Wl1, Wr1, bt1_h, bt1_l, 6);
    split_wT <<<(1024 * HD + 255) / 256, gblk, 0, stream>>>(Wl2, Wr2, bt2_h, bt2_l, 9);

    // ---- layer 1: GATv2Conv(64 -> 64, heads=8, concat) + ELU ----
    gemm_2ph<64><<<gemm_grid, gblk, 0, stream>>>(xs_h, xs_l, bt1_h, bt1_l, xlr, N);
    gat_fused<0><<<nblk, gblk, 0, stream>>>(xlr, att1, b1, rowptr, eidx, N,
                                            nullptr, h1_h, h1_l);

    // ---- layer 2: GATv2Conv(512 -> 64, heads=8, mean) ----
    gemm_2ph<512><<<gemm_grid, gblk, 0, stream>>>(h1_h, h1_l, bt2_h, bt2_l, xlr, N);
    gat_fused<1><<<nblk, gblk, 0, stream>>>(xlr, att2, b2, rowptr, eidx, N,
                                            (float*)d_out, nullptr, nullptr);
}

// Round 16
// 279.868 us; speedup vs baseline: 1.4309x; 1.0283x over previous
//
#include <hip/hip_runtime.h>
#include <hip/hip_fp16.h>
#include <math.h>

#define DD 64      // per-head channels
#define HH 8       // heads
#define HD 512     // HH*DD
#define NC 1024    // combined xl|xr row width

typedef __attribute__((ext_vector_type(8))) short bf16x8;
typedef __attribute__((ext_vector_type(4))) float f32x4;
typedef __attribute__((ext_vector_type(8))) unsigned short ushort8;

// ---------------------------------------------------------------------------
// bf16 split helpers (round-to-nearest-even)
// ---------------------------------------------------------------------------
__device__ __forceinline__ ushort bf16_rne(float f) {
    uint u = __float_as_uint(f);
    u += 0x7fffu + ((u >> 16) & 1u);
    return (ushort)(u >> 16);
}
__device__ __forceinline__ float bf16_tof(ushort h) {
    return __uint_as_float(((uint)h) << 16);
}
__device__ __forceinline__ float h2f(ushort u) {
    __half h; *reinterpret_cast<ushort*>(&h) = u; return __half2float(h);
}
// packed fp16 max — ROCm 7.2 headers lack __hmax2; emit v_pk_max_f16 directly
__device__ __forceinline__ __half2 pk_max(__half2 a, __half2 b) {
    __half2 r;
    asm("v_pk_max_f16 %0, %1, %2" : "=v"(r) : "v"(a), "v"(b));
    return r;
}

// elementwise fp32 -> (hi, lo) bf16 pair
__global__ __launch_bounds__(256) void split_mat(const float* __restrict__ in,
                                                 ushort* __restrict__ hi,
                                                 ushort* __restrict__ lo, int total)
{
    const int i = blockIdx.x * 256 + threadIdx.x;
    if (i >= total) return;
    const float f = in[i];
    const ushort h = bf16_rne(f);
    hi[i] = h;
    lo[i] = bf16_rne(f - bf16_tof(h));
}

// W0,W1: [K][512] fp32 -> Bt: [1024][K] bf16 hi/lo (transposed, concatenated)
__global__ __launch_bounds__(256) void split_wT(const float* __restrict__ W0,
                                                const float* __restrict__ W1,
                                                ushort* __restrict__ hi,
                                                ushort* __restrict__ lo, int kshift)
{
    const int K = 1 << kshift;
    const int i = blockIdx.x * 256 + threadIdx.x;    // i = c*K + k
    if (i >= 1024 * K) return;
    const int c = i >> kshift, k = i & (K - 1);
    const float* W = (c < 512) ? W0 : W1;
    const float f = W[(size_t)k * 512 + (c & 511)];
    const ushort h = bf16_rne(f);
    hi[i] = h;
    lo[i] = bf16_rne(f - bf16_tof(h));
}

// ---------------------------------------------------------------------------
// bf16x3 split-precision MFMA GEMM (round-12 proven version, 65 us @ K=512).
// Staging via global_load_lds width=16; LDS dest linear, XOR swizzle applied
// to the GLOBAL source chunk (m173 pattern): LDS(row,c) = G(row, c^(row&7)).
// ---------------------------------------------------------------------------
__global__ __launch_bounds__(256) void gemm_bf16x3(
    const ushort* __restrict__ Ah, const ushort* __restrict__ Al,
    const ushort* __restrict__ Bh, const ushort* __restrict__ Bl,
    __half* __restrict__ C, int M, int K)
{
    __shared__ __align__(16) ushort lAh[128 * 64];
    __shared__ __align__(16) ushort lAl[128 * 64];
    __shared__ __align__(16) ushort lBh[128 * 64];
    __shared__ __align__(16) ushort lBl[128 * 64];

    const int nwg = gridDim.x;                        // 8*MT, divisible by 8
    const int wg  = (blockIdx.x & 7) * (nwg >> 3) + (blockIdx.x >> 3);
    const int ntile = wg & 7, mtile = wg >> 3;
    const int bm = mtile * 128, bn = ntile * 128;

    const int tid  = threadIdx.x;
    const int wid  = tid >> 6;            // 0..3
    const int lane = tid & 63;
    const int wr = wid >> 1, wc = wid & 1;   // 2x2 wave quadrants (64x64)
    const int l15 = lane & 15, g = lane >> 4;

    const int rsub = lane >> 3;              // row within 8-row group (0..7)
    const int gch  = (lane & 7) ^ rsub;      // pre-swizzled source k-chunk

    f32x4 acc[4][4] = {};

    for (int k0 = 0; k0 < K; k0 += 64) {
        __syncthreads();                   // previous iter's LDS reads done
        #pragma unroll
        for (int q = 0; q < 4; ++q) {
            const int rowb = wid * 32 + q * 8;        // wave-uniform base row
            const int row  = rowb + rsub;
            const size_t ga = (size_t)min(bm + row, M - 1) * K + k0 + gch * 8;
            const size_t gb = (size_t)(bn + row) * K + k0 + gch * 8;
            __builtin_amdgcn_global_load_lds(
                (const __attribute__((address_space(1))) void*)(Ah + ga),
                (__attribute__((address_space(3))) void*)(lAh + rowb * 64), 16, 0, 0);
            __builtin_amdgcn_global_load_lds(
                (const __attribute__((address_space(1))) void*)(Al + ga),
                (__attribute__((address_space(3))) void*)(lAl + rowb * 64), 16, 0, 0);
            __builtin_amdgcn_global_load_lds(
                (const __attribute__((address_space(1))) void*)(Bh + gb),
                (__attribute__((address_space(3))) void*)(lBh + rowb * 64), 16, 0, 0);
            __builtin_amdgcn_global_load_lds(
                (const __attribute__((address_space(1))) void*)(Bl + gb),
                (__attribute__((address_space(3))) void*)(lBl + rowb * 64), 16, 0, 0);
        }
        __syncthreads();                   // drains vmcnt (compiler-emitted)

        #pragma unroll
        for (int kk = 0; kk < 2; ++kk) {
            bf16x8 ah[4], al[4], bh[4], bl[4];
            #pragma unroll
            for (int m = 0; m < 4; ++m) {
                const int row = wr * 64 + m * 16 + l15;
                const int sc  = (kk * 4 + g) ^ (row & 7);
                const int idx = row * 64 + (sc << 3);
                ah[m] = *(const bf16x8*)(lAh + idx);
                al[m] = *(const bf16x8*)(lAl + idx);
            }
            #pragma unroll
            for (int n = 0; n < 4; ++n) {
                const int row = wc * 64 + n * 16 + l15;
                const int sc  = (kk * 4 + g) ^ (row & 7);
                const int idx = row * 64 + (sc << 3);
                bh[n] = *(const bf16x8*)(lBh + idx);
                bl[n] = *(const bf16x8*)(lBl + idx);
            }
            #pragma unroll
            for (int m = 0; m < 4; ++m)
                #pragma unroll
                for (int n = 0; n < 4; ++n) {
                    acc[m][n] = __builtin_amdgcn_mfma_f32_16x16x32_bf16(
                                    ah[m], bh[n], acc[m][n], 0, 0, 0);
                    acc[m][n] = __builtin_amdgcn_mfma_f32_16x16x32_bf16(
                                    ah[m], bl[n], acc[m][n], 0, 0, 0);
                    acc[m][n] = __builtin_amdgcn_mfma_f32_16x16x32_bf16(
                                    al[m], bh[n], acc[m][n], 0, 0, 0);
                }
        }
    }

    #pragma unroll
    for (int m = 0; m < 4; ++m) {
        #pragma unroll
        for (int i = 0; i < 4; ++i) {
            const int row = bm + wr * 64 + m * 16 + g * 4 + i;
            if (row >= M) continue;
            __half* cp = C + (size_t)row * NC + bn + wc * 64 + l15;
            #pragma unroll
            for (int n = 0; n < 4; ++n)
                cp[n * 16] = __float2half_rn(acc[m][n][i]);
        }
    }
}

// ---------------------------------------------------------------------------
// CSR build (per launch; edge list identical for both layers).
// ---------------------------------------------------------------------------
__global__ __launch_bounds__(256) void hist_deg(const int* __restrict__ dsts,
                                                int E, int ET, int* __restrict__ deg)
{
    const int w = blockIdx.x * blockDim.x + threadIdx.x;
    if (w >= ET) return;
    const int d = (w < E) ? dsts[w] : (w - E);   // w >= E: virtual self-loop
    atomicAdd(&deg[d], 1);
}

// single-block exclusive scan, 1024-wide
__global__ __launch_bounds__(1024) void scan_rowptr(const int* __restrict__ deg,
                                                    int* __restrict__ rowptr,
                                                    int* __restrict__ cursor, int n)
{
    __shared__ int sums[1024];
    const int tid   = threadIdx.x;
    const int chunk = (n + 1023) / 1024;
    const int lo = min(tid * chunk, n), hi = min(lo + chunk, n);

    int s = 0;
    for (int i = lo; i < hi; ++i) s += deg[i];
    sums[tid] = s;
    __syncthreads();

    for (int off = 1; off < 1024; off <<= 1) {
        const int t = (tid >= off) ? sums[tid - off] : 0;
        __syncthreads();
        sums[tid] += t;
        __syncthreads();
    }

    int run = sums[tid] - s;   // exclusive prefix of this chunk
    for (int i = lo; i < hi; ++i) {
        rowptr[i] = run;
        cursor[i] = run;
        run += deg[i];
    }
    if (tid == 1023) rowptr[n] = run;   // == ET
}

__global__ __launch_bounds__(256) void scatter_csr(const int* __restrict__ srcs,
                                                   const int* __restrict__ dsts,
                                                   int E, int ET,
                                                   int* __restrict__ cursor,
                                                   int* __restrict__ eidx)
{
    const int w = blockIdx.x * blockDim.x + threadIdx.x;
    if (w >= ET) return;
    int s, d;
    if (w < E) { s = srcs[w]; d = dsts[w]; }
    else       { s = w - E;   d = s; }
    const int pos = atomicAdd(&cursor[d], 1);
    eidx[pos] = s;
}

// ---------------------------------------------------------------------------
// Fused GATv2 edge pipeline + epilogue.
// ONE wave per dst node; lane owns 8 contiguous channels (head = lane>>3).
// Logit path in packed fp16 (__half2): leaky_relu(t) = max(t, 0.2t),
// 4x(hadd2+hmul2+pk_max+hfma2) replaces ~32 scalar VALU ops per edge.
// Aggregation stays fp32. 2-edge unrolled, branch-free clamped prefetch.
// ---------------------------------------------------------------------------
__device__ __forceinline__ void edge_step_pk(const ushort8 v,
                                             const __half2* __restrict__ ra,
                                             const __half2* __restrict__ at,
                                             const __half2 c02,
                                             float* __restrict__ acc, float& den)
{
    float vf[8];
    __half2 sacc = __floats2half2_rn(0.f, 0.f);
    #pragma unroll
    for (int j = 0; j < 4; ++j) {
        ushort2 u = make_ushort2(v[2 * j], v[2 * j + 1]);
        const __half2 vh = *reinterpret_cast<const __half2*>(&u);
        const float2 vv = __half22float2(vh);
        vf[2 * j] = vv.x; vf[2 * j + 1] = vv.y;
        __half2 t = __hadd2(vh, ra[j]);
        t = pk_max(t, __hmul2(t, c02));           // leaky_relu(0.2), both signs
        sacc = __hfma2(t, at[j], sacc);
    }
    float s = __low2float(sacc) + __high2float(sacc);
    s += __shfl_xor(s, 1, 64);                    // reduce within 8-lane head
    s += __shfl_xor(s, 2, 64);
    s += __shfl_xor(s, 4, 64);
    const float p = __expf(s);                    // logits O(1): no max shift
    den += p;
    #pragma unroll
    for (int j = 0; j < 8; ++j) acc[j] = fmaf(p, vf[j], acc[j]);
}

template<int MODE>
__global__ __launch_bounds__(256) void gat_fused(
    const __half* __restrict__ xlr, const float* __restrict__ att,
    const float* __restrict__ bias, const int* __restrict__ rowptr,
    const int* __restrict__ eidx, int n, float* __restrict__ out,
    ushort* __restrict__ oh, ushort* __restrict__ ol)
{
    const int d    = (blockIdx.x * blockDim.x + threadIdx.x) >> 6;
    const int lane = threadIdx.x & 63;
    if (d >= n) return;

    const int o = lane * 8;                  // channels [o, o+8)
    const __half2 c02 = __floats2half2_rn(0.2f, 0.2f);

    // xr row (fp16) and att (fp32->fp16) -> packed registers
    __half2 ra[4], at[4];
    {
        const ushort8 rv = *(const ushort8*)((const ushort*)xlr + (size_t)d * NC + 512 + o);
        #pragma unroll
        for (int j = 0; j < 4; ++j) {
            ushort2 u = make_ushort2(rv[2 * j], rv[2 * j + 1]);
            ra[j] = *reinterpret_cast<const __half2*>(&u);
            at[j] = __floats2half2_rn(att[o + 2 * j], att[o + 2 * j + 1]);
        }
    }

    float acc[8] = {};
    float den = 0.f;

    const int start = rowptr[d];
    const int end   = rowptr[d + 1];         // deg >= 1 (self-loop)
    const int last  = end - 1;
    const ushort* xb = (const ushort*)xlr;

    ushort8 v0 = *(const ushort8*)(xb + ((size_t)eidx[start] << 10) + o);
    ushort8 v1 = *(const ushort8*)(xb + ((size_t)eidx[min(start + 1, last)] << 10) + o);

    int e = start;
    for (; e + 1 < end; e += 2) {
        const int i2 = min(e + 2, last), i3 = min(e + 3, last);
        const ushort8 n0 = *(const ushort8*)(xb + ((size_t)eidx[i2] << 10) + o);
        const ushort8 n1 = *(const ushort8*)(xb + ((size_t)eidx[i3] << 10) + o);
        edge_step_pk(v0, ra, at, c02, acc, den);
        edge_step_pk(v1, ra, at, c02, acc, den);
        v0 = n0; v1 = n1;
    }
    if (e < end) edge_step_pk(v0, ra, at, c02, acc, den);

    const float inv = 1.f / den;

    if (MODE == 0) {
        // elu(agg + b1), emitted as bf16 hi/lo split for the next GEMM
        float bv[8];
        *(float4*)&bv[0] = *(const float4*)(bias + o);
        *(float4*)&bv[4] = *(const float4*)(bias + o + 4);
        ushort8 hx, lx;
        #pragma unroll
        for (int j = 0; j < 8; ++j) {
            const float u = fmaf(acc[j], inv, bv[j]);
            const float w = u > 0.f ? u : expm1f(u);
            const ushort h = bf16_rne(w);
            hx[j] = h;
            lx[j] = bf16_rne(w - bf16_tof(h));
        }
        *(ushort8*)(oh + (size_t)d * HD + o) = hx;
        *(ushort8*)(ol + (size_t)d * HD + o) = lx;
    } else {
        // mean over 8 heads: reduce across lane bits 3,4,5
        float m[8];
        #pragma unroll
        for (int j = 0; j < 8; ++j) m[j] = acc[j] * inv;
        #pragma unroll
        for (int j = 0; j < 8; ++j) {
            m[j] += __shfl_xor(m[j], 8,  64);
            m[j] += __shfl_xor(m[j], 16, 64);
            m[j] += __shfl_xor(m[j], 32, 64);
        }
        if (lane < 8) {                      // lane covers channels lane*8..+7
            const int c = lane * 8;
            float4 r0, r1;
            r0.x = fmaf(m[0], 0.125f, bias[c + 0]);
            r0.y = fmaf(m[1], 0.125f, bias[c + 1]);
            r0.z = fmaf(m[2], 0.125f, bias[c + 2]);
            r0.w = fmaf(m[3], 0.125f, bias[c + 3]);
            r1.x = fmaf(m[4], 0.125f, bias[c + 4]);
            r1.y = fmaf(m[5], 0.125f, bias[c + 5]);
            r1.z = fmaf(m[6], 0.125f, bias[c + 6]);
            r1.w = fmaf(m[7], 0.125f, bias[c + 7]);
            *(float4*)(out + (size_t)d * DD + c)     = r0;
            *(float4*)(out + (size_t)d * DD + c + 4) = r1;
        }
    }
}

// ---------------------------------------------------------------------------
extern "C" void kernel_launch(void* const* d_in, const int* in_sizes, int n_in,
                              void* d_out, int out_size, void* d_ws, size_t ws_size,
                              hipStream_t stream)
{
    const float* x    = (const float*)d_in[0];
    const int*   ei   = (const int*)  d_in[1];
    const float* Wl1  = (const float*)d_in[2];
    const float* Wr1  = (const float*)d_in[3];
    const float* att1 = (const float*)d_in[4];
    const float* b1   = (const float*)d_in[5];
    const float* Wl2  = (const float*)d_in[6];
    const float* Wr2  = (const float*)d_in[7];
    const float* att2 = (const float*)d_in[8];
    const float* b2   = (const float*)d_in[9];

    const int N  = in_sizes[0] / DD;   // 20000
    const int E  = in_sizes[1] / 2;    // 320000
    const int ET = E + N;              // edges + self-loops

    const int* srcs = ei;
    const int* dsts = ei + E;

    // ---- workspace layout ----
    __half* xlr   = (__half*)d_ws;                      // N*1024 f16 (41 MB)
    ushort* xs_h  = (ushort*)(xlr + (size_t)N * NC);    // N*64
    ushort* xs_l  = xs_h  + (size_t)N * DD;             // N*64
    ushort* h1_h  = xs_l  + (size_t)N * DD;             // N*512
    ushort* h1_l  = h1_h  + (size_t)N * HD;             // N*512
    ushort* bt1_h = h1_l  + (size_t)N * HD;             // 1024*64
    ushort* bt1_l = bt1_h + 1024 * DD;                  // 1024*64
    ushort* bt2_h = bt1_l + 1024 * DD;                  // 1024*512
    ushort* bt2_l = bt2_h + 1024 * HD;                  // 1024*512
    int* rowptr = (int*)(bt2_l + 1024 * HD);            // N+1
    int* deg    = rowptr + (N + 1);                     // N
    int* cursor = deg + N;                              // N
    int* eidx   = cursor + N;                           // ET

    const dim3 gblk(256);
    const int  eblk  = (ET + 255) / 256;
    const int  nblk  = (N + 3) / 4;            // one WAVE per node, 4 nodes/block
    const int  MT    = (N + 127) / 128;        // 157
    const int  gemm_grid = 8 * MT;             // 1256, divisible by 8

    // ---- CSR build (shared by both layers) ----
    hipMemsetAsync(deg, 0, (size_t)N * sizeof(int), stream);
    hist_deg   <<<eblk, gblk, 0, stream>>>(dsts, E, ET, deg);
    scan_rowptr<<<1, 1024, 0, stream>>>(deg, rowptr, cursor, N);
    scatter_csr<<<eblk, gblk, 0, stream>>>(srcs, dsts, E, ET, cursor, eidx);

    // ---- split inputs / weights to bf16 hi/lo ----
    split_mat<<<(N * DD + 255) / 256, gblk, 0, stream>>>(x, xs_h, xs_l, N * DD);
    split_wT <<<(1024 * DD + 255) / 256, gblk, 0, stream>>>(Wl1, Wr1, bt1_h, bt1_l, 6);
    split_wT <<<(1024 * HD + 255) / 256, gblk, 0, stream>>>(Wl2, Wr2, bt2_h, bt2_l, 9);

    // ---- layer 1: GATv2Conv(64 -> 64, heads=8, concat) + ELU ----
    gemm_bf16x3<<<gemm_grid, gblk, 0, stream>>>(xs_h, xs_l, bt1_h, bt1_l, xlr, N, DD);
    gat_fused<0><<<nblk, gblk, 0, stream>>>(xlr, att1, b1, rowptr, eidx, N,
                                            nullptr, h1_h, h1_l);

    // ---- layer 2: GATv2Conv(512 -> 64, heads=8, mean) ----
    gemm_bf16x3<<<gemm_grid, gblk, 0, stream>>>(h1_h, h1_l, bt2_h, bt2_l, xlr, N, HD);
    gat_fused<1><<<nblk, gblk, 0, stream>>>(xlr, att2, b2, rowptr, eidx, N,
                                            (float*)d_out, nullptr, nullptr);
}